// Round 1
// baseline (1429.235 us; speedup 1.0000x reference)
//
#include <hip/hip_runtime.h>

// Problem constants (CausalSelfAttention: B=2, S=2048, D=1024, H=16, HD=64)
#define B_  2
#define S_  2048
#define D_  1024
#define H_  16
#define HD_ 64
#define TD_ 3072   // 3*D

// ---------------------------------------------------------------------------
// GEMM: C[M,N] = A[M,K] @ W[K,N] + bias[N]   (all row-major, fp32)
// Block = 256 threads, tile 64x64, BK=16, 4x4 per-thread micro-tile.
// M,N divisible by 64, K by 16 (true for both GEMMs here) -> no bounds checks.
// ---------------------------------------------------------------------------
__global__ __launch_bounds__(256)
void gemm_bias_kernel(const float* __restrict__ A, const float* __restrict__ W,
                      const float* __restrict__ bias, float* __restrict__ C,
                      int M, int N, int K) {
    __shared__ float As[16][64 + 1];  // [k][m], +1 pad breaks stride conflicts
    __shared__ float Bs[16][64];      // [k][n]

    const int tid = threadIdx.x;
    const int tx = tid & 15;          // micro-tile col group
    const int ty = tid >> 4;          // micro-tile row group
    const int rowBase = blockIdx.y * 64;
    const int colBase = blockIdx.x * 64;

    float acc[4][4] = {};

    for (int k0 = 0; k0 < K; k0 += 16) {
        // A tile 64x16: float4 along k, 4 elems/thread
        {
            int r  = tid >> 2;         // 0..63
            int kg = (tid & 3) * 4;    // 0,4,8,12
            const float4 av = *(const float4*)(A + (size_t)(rowBase + r) * K + k0 + kg);
            As[kg + 0][r] = av.x;
            As[kg + 1][r] = av.y;
            As[kg + 2][r] = av.z;
            As[kg + 3][r] = av.w;
        }
        // B tile 16x64: coalesced rows, 4 elems/thread
        {
            int col = tid & 63;
            int r0  = tid >> 6;        // 0..3
            #pragma unroll
            for (int r = 0; r < 4; ++r) {
                int kr = r * 4 + r0;
                Bs[kr][col] = W[(size_t)(k0 + kr) * N + colBase + col];
            }
        }
        __syncthreads();
        #pragma unroll
        for (int kk = 0; kk < 16; ++kk) {
            float a[4], b[4];
            #pragma unroll
            for (int i = 0; i < 4; ++i) a[i] = As[kk][ty * 4 + i];  // broadcast x16
            #pragma unroll
            for (int j = 0; j < 4; ++j) b[j] = Bs[kk][tx * 4 + j];  // 2-way (free)
            #pragma unroll
            for (int i = 0; i < 4; ++i)
                #pragma unroll
                for (int j = 0; j < 4; ++j)
                    acc[i][j] += a[i] * b[j];
        }
        __syncthreads();
    }

    #pragma unroll
    for (int i = 0; i < 4; ++i) {
        int row = rowBase + ty * 4 + i;
        #pragma unroll
        for (int j = 0; j < 4; ++j) {
            int col = colBase + tx * 4 + j;
            C[(size_t)row * N + col] = acc[i][j] + bias[col];
        }
    }
}

// ---------------------------------------------------------------------------
// Flash causal attention. qkv layout: [B*S, 3D] rows; q at col h*HD+d,
// k at D + h*HD+d, v at 2D + h*HD+d.  out: [B,S,D] with col = h*HD + d.
// Grid: (S/64, H, B). Block: 256 threads. BQ=64, BKV=32.
// Thread t: row = t&63 (q row in tile), cg = t>>6 (col/k group) -> cg is
// wave-uniform, so Ks/Vs reads are broadcasts; Qs/Ss strides 65/33 are
// conflict-free across rows.
// ---------------------------------------------------------------------------
__global__ __launch_bounds__(256)
void flash_attn_kernel(const float* __restrict__ qkv, float* __restrict__ out) {
    const int qt  = blockIdx.x;   // 0..31
    const int h   = blockIdx.y;   // 0..15
    const int b   = blockIdx.z;   // 0..1
    const int tid = threadIdx.x;
    const int row = tid & 63;
    const int cg  = tid >> 6;     // 0..3, wave-uniform

    __shared__ float Qs[64][HD_ + 1];   // 16.64 KB
    __shared__ float Ks[32][HD_];       //  8 KB (broadcast reads only)
    __shared__ float Vs[32][HD_];       //  8 KB (broadcast reads only)
    __shared__ float Ss[64][33];        //  8.45 KB
    __shared__ float m_s[64], l_s[64], alpha_s[64];

    const int qBase = qt * 64;
    const float scale = 0.125f;         // 1/sqrt(64)

    // Load Q tile (pre-scaled)
    {
        int d  = tid & 63;
        int r0 = tid >> 6;
        #pragma unroll
        for (int r = 0; r < 16; ++r) {
            int qr = r * 4 + r0;
            Qs[qr][d] = qkv[(size_t)(b * S_ + qBase + qr) * TD_ + h * HD_ + d] * scale;
        }
    }
    if (tid < 64) { m_s[tid] = -3.0e38f; l_s[tid] = 0.0f; }

    float o[16];
    #pragma unroll
    for (int j = 0; j < 16; ++j) o[j] = 0.0f;

    const int nkt = 2 * qt + 2;   // causal: k-tiles of 32 up to (and incl.) diagonal
    for (int kt = 0; kt < nkt; ++kt) {
        const int kBase = kt * 32;
        // Load K,V tiles 32x64 (coalesced along d)
        {
            int d  = tid & 63;
            int r0 = tid >> 6;
            #pragma unroll
            for (int r = 0; r < 8; ++r) {
                int kr = r * 4 + r0;
                size_t base = (size_t)(b * S_ + kBase + kr) * TD_ + h * HD_ + d;
                Ks[kr][d] = qkv[base + D_];
                Vs[kr][d] = qkv[base + 2 * D_];
            }
        }
        __syncthreads();

        // Scores: thread computes Ss[row][cg*8 + j], j=0..7
        {
            float s[8];
            #pragma unroll
            for (int j = 0; j < 8; ++j) s[j] = 0.0f;
            for (int d = 0; d < HD_; ++d) {
                float qv = Qs[row][d];
                #pragma unroll
                for (int j = 0; j < 8; ++j)
                    s[j] += qv * Ks[cg * 8 + j][d];
            }
            const bool needMask = (kt >= 2 * qt);
            #pragma unroll
            for (int j = 0; j < 8; ++j) {
                int kg = kBase + cg * 8 + j;
                float sv = s[j];
                if (needMask && kg > qBase + row) sv = -3.0e38f;
                Ss[row][cg * 8 + j] = sv;
            }
        }
        __syncthreads();

        // Online-softmax row pass (wave 0 only)
        if (tid < 64) {
            float m_old = m_s[tid];
            float mx = m_old;
            #pragma unroll
            for (int j = 0; j < 32; ++j) mx = fmaxf(mx, Ss[tid][j]);
            float alpha = __expf(m_old - mx);   // first tile: exp(-huge)=0
            float sum = 0.0f;
            #pragma unroll
            for (int j = 0; j < 32; ++j) {
                float p = __expf(Ss[tid][j] - mx);
                Ss[tid][j] = p;
                sum += p;
            }
            m_s[tid]     = mx;
            l_s[tid]     = alpha * l_s[tid] + sum;
            alpha_s[tid] = alpha;
        }
        __syncthreads();

        // O update: o = alpha*o + P@V  (thread owns cols cg*16..cg*16+15)
        {
            float alpha = alpha_s[row];
            #pragma unroll
            for (int j = 0; j < 16; ++j) o[j] *= alpha;
            for (int k = 0; k < 32; ++k) {
                float p = Ss[row][k];
                #pragma unroll
                for (int j = 0; j < 16; ++j)
                    o[j] += p * Vs[k][cg * 16 + j];
            }
        }
        __syncthreads();   // protect Ks/Vs/Ss for next iteration
    }

    const float inv_l = 1.0f / l_s[row];
    size_t outBase = (size_t)(b * S_ + qBase + row) * D_ + h * HD_ + cg * 16;
    #pragma unroll
    for (int j = 0; j < 16; ++j)
        out[outBase + j] = o[j] * inv_l;
}

// ---------------------------------------------------------------------------
extern "C" void kernel_launch(void* const* d_in, const int* in_sizes, int n_in,
                              void* d_out, int out_size, void* d_ws, size_t ws_size,
                              hipStream_t stream) {
    const float* x      = (const float*)d_in[0];  // [B,S,D]
    const float* w_attn = (const float*)d_in[1];  // [D,3D]
    const float* b_attn = (const float*)d_in[2];  // [3D]
    const float* w_proj = (const float*)d_in[3];  // [D,D]
    const float* b_proj = (const float*)d_in[4];  // [D]
    float* out = (float*)d_out;                   // [B,S,D]

    // Workspace: qkv [B*S,3D] = 48 MB, attn_out [B*S,D] = 16 MB (64 MB total)
    float* qkv  = (float*)d_ws;
    float* attn = qkv + (size_t)B_ * S_ * TD_;

    const int M = B_ * S_;   // 4096

    // 1) QKV projection: [4096,1024] @ [1024,3072] + bias
    dim3 g1(TD_ / 64, M / 64);
    gemm_bias_kernel<<<g1, 256, 0, stream>>>(x, w_attn, b_attn, qkv, M, TD_, D_);

    // 2) Causal flash attention
    dim3 g2(S_ / 64, H_, B_);
    flash_attn_kernel<<<g2, 256, 0, stream>>>(qkv, attn);

    // 3) Output projection: [4096,1024] @ [1024,1024] + bias
    dim3 g3(D_ / 64, M / 64);
    gemm_bias_kernel<<<g3, 256, 0, stream>>>(attn, w_proj, b_proj, out, M, D_, D_);
}

// Round 2
// 280.841 us; speedup vs baseline: 5.0891x; 5.0891x over previous
//
#include <hip/hip_runtime.h>

// CausalSelfAttention: B=2, S=2048, D=1024, H=16, HD=64
#define B_  2
#define S_  2048
#define D_  1024
#define H_  16
#define HD_ 64
#define TD_ 3072
#define M_  (B_*S_)   // 4096

using bf16x8 = __attribute__((ext_vector_type(8))) short;   // 8 bf16 = 4 VGPRs
using f32x4  = __attribute__((ext_vector_type(4))) float;   // MFMA C/D

static __device__ __forceinline__ short f2bf(float f) {
    unsigned u = __float_as_uint(f);
    u += 0x7FFFu + ((u >> 16) & 1u);   // round-to-nearest-even
    return (short)(u >> 16);
}

// ---------------------------------------------------------------------------
// cast x (fp32) -> bf16, 4 elems/thread
// ---------------------------------------------------------------------------
__global__ void cast_x_kernel(const float* __restrict__ x, short* __restrict__ xb, int n4) {
    int i = blockIdx.x * blockDim.x + threadIdx.x;
    if (i >= n4) return;
    float4 v = *((const float4*)x + i);
    short4 o;
    o.x = f2bf(v.x); o.y = f2bf(v.y); o.z = f2bf(v.z); o.w = f2bf(v.w);
    *((short4*)xb + i) = o;
}

// ---------------------------------------------------------------------------
// W [K][N] fp32 -> Wt [N][K] bf16  (transpose + cast), 32x32 LDS tile
// ---------------------------------------------------------------------------
__global__ __launch_bounds__(256)
void wtrans_kernel(const float* __restrict__ W, short* __restrict__ Wt, int K, int N) {
    __shared__ float T[32][33];
    int n0 = blockIdx.x * 32, k0 = blockIdx.y * 32;
    int tx = threadIdx.x & 31, ty = threadIdx.x >> 5;
    #pragma unroll
    for (int i = 0; i < 4; ++i)
        T[ty + i * 8][tx] = W[(size_t)(k0 + ty + i * 8) * N + n0 + tx];
    __syncthreads();
    #pragma unroll
    for (int i = 0; i < 4; ++i)
        Wt[(size_t)(n0 + ty + i * 8) * K + k0 + tx] = f2bf(T[tx][ty + i * 8]);
}

// ---------------------------------------------------------------------------
// V [B,H,S,HD] bf16 -> Vt [B,H,HD,S] bf16 (per-plane transpose)
// ---------------------------------------------------------------------------
__global__ __launch_bounds__(256)
void vtrans_kernel(const short* __restrict__ V, short* __restrict__ Vt) {
    __shared__ short T[32][33];
    int p  = blockIdx.z;               // b*H + h
    int s0 = blockIdx.x * 32;
    int d0 = blockIdx.y * 32;
    int tx = threadIdx.x & 31, ty = threadIdx.x >> 5;
    const short* Vp  = V  + (size_t)p * S_ * HD_;
    short*       Vtp = Vt + (size_t)p * HD_ * S_;
    #pragma unroll
    for (int i = 0; i < 4; ++i)
        T[ty + i * 8][tx] = Vp[(s0 + ty + i * 8) * HD_ + d0 + tx];
    __syncthreads();
    #pragma unroll
    for (int i = 0; i < 4; ++i)
        Vtp[(size_t)(d0 + ty + i * 8) * S_ + s0 + tx] = T[tx][ty + i * 8];
}

// ---------------------------------------------------------------------------
// bf16 MFMA GEMM: C[M,N] = A[M,K] @ Bt[N,K]^T + bias
// 128x128 tile, BK=32, 256 threads = 4 waves in 2x2, each wave 64x64 (4x4
// 16x16x32 MFMA tiles). LDS As/Bs [128][32] bf16 (64B rows: frag reads and
// staged writes both land at the 8-cyc b128 floor, no padding needed).
// MODE 0: fp32 C + bias.  MODE 1: scatter to Q(scaled)/K/V bf16 [B,H,S,HD].
// ---------------------------------------------------------------------------
template<int MODE>
__global__ __launch_bounds__(256)
void gemm_mfma_kernel(const short* __restrict__ A, const short* __restrict__ Bt,
                      const float* __restrict__ bias, float* __restrict__ Cf,
                      short* __restrict__ Qo, short* __restrict__ Ko, short* __restrict__ Vo,
                      int M, int N, int K) {
    __shared__ __align__(16) short As[128][32];
    __shared__ __align__(16) short Bs[128][32];

    const int tid  = threadIdx.x;
    const int w    = tid >> 6, lane = tid & 63;
    const int quad = lane >> 4, l16 = lane & 15;
    const int wr = (w >> 1) * 64, wc = (w & 1) * 64;
    const int rowBase = blockIdx.y * 128, colBase = blockIdx.x * 128;

    f32x4 acc[4][4];
    const f32x4 zero = {0.f, 0.f, 0.f, 0.f};
    #pragma unroll
    for (int i = 0; i < 4; ++i)
        #pragma unroll
        for (int j = 0; j < 4; ++j) acc[i][j] = zero;

    const int am0 = tid >> 2;            // staging row (0..63; +64 for 2nd chunk)
    const int akc = (tid & 3) * 8;       // staging k offset (bf16 units)

    for (int k0 = 0; k0 < K; k0 += 32) {
        uint4 a0 = *(const uint4*)(A  + (size_t)(rowBase + am0)      * K + k0 + akc);
        uint4 a1 = *(const uint4*)(A  + (size_t)(rowBase + am0 + 64) * K + k0 + akc);
        uint4 b0 = *(const uint4*)(Bt + (size_t)(colBase + am0)      * K + k0 + akc);
        uint4 b1 = *(const uint4*)(Bt + (size_t)(colBase + am0 + 64) * K + k0 + akc);
        __syncthreads();
        *(uint4*)&As[am0][akc]      = a0;
        *(uint4*)&As[am0 + 64][akc] = a1;
        *(uint4*)&Bs[am0][akc]      = b0;
        *(uint4*)&Bs[am0 + 64][akc] = b1;
        __syncthreads();

        bf16x8 af[4], bf[4];
        #pragma unroll
        for (int t = 0; t < 4; ++t) {
            af[t] = *(const bf16x8*)&As[wr + t * 16 + l16][quad * 8];
            bf[t] = *(const bf16x8*)&Bs[wc + t * 16 + l16][quad * 8];
        }
        #pragma unroll
        for (int i = 0; i < 4; ++i)
            #pragma unroll
            for (int j = 0; j < 4; ++j)
                acc[i][j] = __builtin_amdgcn_mfma_f32_16x16x32_bf16(af[i], bf[j], acc[i][j], 0, 0, 0);
    }

    if (MODE == 0) {
        #pragma unroll
        for (int i = 0; i < 4; ++i) {
            int row = rowBase + wr + i * 16 + quad * 4;
            #pragma unroll
            for (int j = 0; j < 4; ++j) {
                int col = colBase + wc + j * 16 + l16;
                float bv = bias[col];
                #pragma unroll
                for (int r = 0; r < 4; ++r)
                    Cf[(size_t)(row + r) * N + col] = acc[i][j][r] + bv;
            }
        }
    } else {
        #pragma unroll
        for (int j = 0; j < 4; ++j) {
            int col = colBase + wc + j * 16 + l16;
            int sel = col >> 10, cr = col & 1023;
            int h = cr >> 6, d = cr & 63;
            float bv  = bias[col];
            short* dst = (sel == 0) ? Qo : (sel == 1) ? Ko : Vo;
            float  scl = (sel == 0) ? 0.125f : 1.0f;   // softmax scale folded into Q
            #pragma unroll
            for (int i = 0; i < 4; ++i) {
                int row = rowBase + wr + i * 16 + quad * 4;
                #pragma unroll
                for (int r = 0; r < 4; ++r) {
                    int rw = row + r;
                    int bb = rw >> 11, s = rw & 2047;
                    dst[((size_t)(bb * H_ + h) * S_ + s) * HD_ + d] =
                        f2bf((acc[i][j][r] + bv) * scl);
                }
            }
        }
    }
}

// ---------------------------------------------------------------------------
// MFMA causal flash attention. BQ=64 (4 waves x 16 rows), BKV=64.
// Q frags register-resident; K tile [kv][d] and V^T tile [d][kv] in LDS
// (stride 72 bf16 = 144 B -> b128 reads/writes at the 8-cyc floor).
// Online softmax fully in registers (shfl_xor over 16-lane groups).
// P -> LDS bf16 -> A-frag round trip (verified m120 pattern).
// qt reversed so heaviest causal blocks dispatch first.
// ---------------------------------------------------------------------------
__global__ __launch_bounds__(256)
void flash_mfma_kernel(const short* __restrict__ Qg, const short* __restrict__ Kg,
                       const short* __restrict__ Vtg, short* __restrict__ Ob) {
    __shared__ __align__(16) short Ks[64][72];
    __shared__ __align__(16) short Vs[64][72];   // Vs[d][kv]
    __shared__ __align__(16) short Ps[64][72];

    const int qt = (int)(gridDim.x - 1) - (int)blockIdx.x;
    const int h = blockIdx.y, b = blockIdx.z;
    const int tid  = threadIdx.x;
    const int w    = tid >> 6, lane = tid & 63;
    const int quad = lane >> 4, l16 = lane & 15;
    const int qBase = qt * 64;
    const size_t plane = (size_t)(b * H_ + h) * S_ * HD_;

    // Q A-fragments (already scaled by 1/sqrt(HD) at GEMM1 epilogue)
    bf16x8 qa0, qa1;
    {
        const short* qrow = Qg + plane + (size_t)(qBase + w * 16 + l16) * HD_;
        qa0 = *(const bf16x8*)(qrow + quad * 8);
        qa1 = *(const bf16x8*)(qrow + 32 + quad * 8);
    }

    f32x4 o[4];
    const f32x4 zero = {0.f, 0.f, 0.f, 0.f};
    #pragma unroll
    for (int i = 0; i < 4; ++i) o[i] = zero;
    float m_r[4] = {-3.0e38f, -3.0e38f, -3.0e38f, -3.0e38f};
    float l_r[4] = {0.f, 0.f, 0.f, 0.f};

    const int c0 = tid, c1 = tid + 256;   // 512 16B-chunks per 64x64 tile

    for (int kt = 0; kt <= qt; ++kt) {
        const int kBase = kt * 64;
        // ---- stage K -> Ks[kv][d], Vt -> Vs[d][kv] ----
        {
            int kv0 = c0 >> 3, dc0 = (c0 & 7) * 8;
            int kv1 = c1 >> 3, dc1 = (c1 & 7) * 8;
            uint4 ka = *(const uint4*)(Kg  + plane + (size_t)(kBase + kv0) * HD_ + dc0);
            uint4 kb = *(const uint4*)(Kg  + plane + (size_t)(kBase + kv1) * HD_ + dc1);
            uint4 va = *(const uint4*)(Vtg + plane + (size_t)kv0 * S_ + kBase + dc0);
            uint4 vb = *(const uint4*)(Vtg + plane + (size_t)kv1 * S_ + kBase + dc1);
            __syncthreads();   // previous iteration's reads complete
            *(uint4*)&Ks[kv0][dc0] = ka;
            *(uint4*)&Ks[kv1][dc1] = kb;
            *(uint4*)&Vs[kv0][dc0] = va;
            *(uint4*)&Vs[kv1][dc1] = vb;
            __syncthreads();
        }

        // ---- S = Q K^T (each wave: its 16 rows x 64 cols) ----
        f32x4 s[4];
        #pragma unroll
        for (int ct = 0; ct < 4; ++ct) {
            bf16x8 k0f = *(const bf16x8*)&Ks[ct * 16 + l16][quad * 8];
            bf16x8 k1f = *(const bf16x8*)&Ks[ct * 16 + l16][32 + quad * 8];
            f32x4 a = zero;
            a = __builtin_amdgcn_mfma_f32_16x16x32_bf16(qa0, k0f, a, 0, 0, 0);
            a = __builtin_amdgcn_mfma_f32_16x16x32_bf16(qa1, k1f, a, 0, 0, 0);
            s[ct] = a;
        }

        // causal mask: only the diagonal tile needs it
        if (kt == qt) {
            int qg = qBase + w * 16 + quad * 4;
            #pragma unroll
            for (int ct = 0; ct < 4; ++ct) {
                int kvg = kBase + ct * 16 + l16;
                #pragma unroll
                for (int r = 0; r < 4; ++r)
                    if (kvg > qg + r) s[ct][r] = -3.0e38f;
            }
        }

        // ---- online softmax, register-resident ----
        float p[4][4];
        #pragma unroll
        for (int r = 0; r < 4; ++r) {
            float mx = fmaxf(fmaxf(s[0][r], s[1][r]), fmaxf(s[2][r], s[3][r]));
            #pragma unroll
            for (int off = 1; off < 16; off <<= 1)
                mx = fmaxf(mx, __shfl_xor(mx, off));
            float m_new = fmaxf(m_r[r], mx);
            float alpha = __expf(m_r[r] - m_new);
            float rs = 0.f;
            #pragma unroll
            for (int ct = 0; ct < 4; ++ct) {
                float pv = __expf(s[ct][r] - m_new);
                p[ct][r] = pv; rs += pv;
            }
            #pragma unroll
            for (int off = 1; off < 16; off <<= 1)
                rs += __shfl_xor(rs, off);
            l_r[r] = l_r[r] * alpha + rs;
            m_r[r] = m_new;
            #pragma unroll
            for (int dt = 0; dt < 4; ++dt) o[dt][r] *= alpha;
        }

        // ---- P -> LDS (own wave's rows only; no barrier needed) ----
        #pragma unroll
        for (int ct = 0; ct < 4; ++ct)
            #pragma unroll
            for (int r = 0; r < 4; ++r)
                Ps[w * 16 + quad * 4 + r][ct * 16 + l16] = f2bf(p[ct][r]);

        // ---- O += P V ----
        #pragma unroll
        for (int kc = 0; kc < 2; ++kc) {
            bf16x8 pa = *(const bf16x8*)&Ps[w * 16 + l16][kc * 32 + quad * 8];
            #pragma unroll
            for (int dt = 0; dt < 4; ++dt) {
                bf16x8 vf = *(const bf16x8*)&Vs[dt * 16 + l16][kc * 32 + quad * 8];
                o[dt] = __builtin_amdgcn_mfma_f32_16x16x32_bf16(pa, vf, o[dt], 0, 0, 0);
            }
        }
    }

    // ---- epilogue: O / l -> attnb bf16 [B*S][D], col = h*64 + d ----
    short* orow = Ob + (size_t)(b * S_ + qBase + w * 16 + quad * 4) * D_ + h * HD_;
    #pragma unroll
    for (int r = 0; r < 4; ++r) {
        float inv_l = 1.0f / l_r[r];
        #pragma unroll
        for (int dt = 0; dt < 4; ++dt)
            orow[(size_t)r * D_ + dt * 16 + l16] = f2bf(o[dt][r] * inv_l);
    }
}

// ---------------------------------------------------------------------------
extern "C" void kernel_launch(void* const* d_in, const int* in_sizes, int n_in,
                              void* d_out, int out_size, void* d_ws, size_t ws_size,
                              hipStream_t stream) {
    const float* x      = (const float*)d_in[0];
    const float* w_attn = (const float*)d_in[1];
    const float* b_attn = (const float*)d_in[2];
    const float* w_proj = (const float*)d_in[3];
    const float* b_proj = (const float*)d_in[4];
    float* out = (float*)d_out;

    char* ws = (char*)d_ws;
    short* xb  = (short*)ws; ws += (size_t)M_ * D_ * 2;    // 8 MB
    short* wat = (short*)ws; ws += (size_t)TD_ * D_ * 2;   // 6 MB
    short* wpt = (short*)ws; ws += (size_t)D_ * D_ * 2;    // 2 MB
    short* qg  = (short*)ws; ws += (size_t)M_ * D_ * 2;    // 8 MB
    short* kg  = (short*)ws; ws += (size_t)M_ * D_ * 2;    // 8 MB
    short* vg  = (short*)ws; ws += (size_t)M_ * D_ * 2;    // 8 MB
    short* vtg = (short*)ws; ws += (size_t)M_ * D_ * 2;    // 8 MB
    short* atb = (short*)ws; ws += (size_t)M_ * D_ * 2;    // 8 MB  (56 MB total)

    // 1) casts / transposes
    cast_x_kernel<<<(M_ * D_ / 4 + 255) / 256, 256, 0, stream>>>(x, xb, M_ * D_ / 4);
    wtrans_kernel<<<dim3(TD_ / 32, D_ / 32), 256, 0, stream>>>(w_attn, wat, D_, TD_);
    wtrans_kernel<<<dim3(D_ / 32, D_ / 32), 256, 0, stream>>>(w_proj, wpt, D_, D_);

    // 2) QKV projection -> q (scaled) / k / v bf16 [B,H,S,HD]
    gemm_mfma_kernel<1><<<dim3(TD_ / 128, M_ / 128), 256, 0, stream>>>(
        xb, wat, b_attn, nullptr, qg, kg, vg, M_, TD_, D_);

    // 3) V -> V^T [B,H,HD,S]
    vtrans_kernel<<<dim3(S_ / 32, HD_ / 32, B_ * H_), 256, 0, stream>>>(vg, vtg);

    // 4) causal flash attention (MFMA) -> atb bf16 [B*S][D]
    flash_mfma_kernel<<<dim3(S_ / 64, H_, B_), 256, 0, stream>>>(qg, kg, vtg, atb);

    // 5) output projection -> fp32 out
    gemm_mfma_kernel<0><<<dim3(D_ / 128, M_ / 128), 256, 0, stream>>>(
        atb, wpt, b_proj, out, nullptr, nullptr, nullptr, M_, D_, D_);
}